// Round 9
// baseline (133.892 us; speedup 1.0000x reference)
//
#include <hip/hip_runtime.h>

// GIB layer: B=2, N=65536, M=8192, K=32; 16 each of cy/cone/disk/ellip gibs;
// out = mean_k(gib_vals) @ lambdas -> (B, M, 16). fp32 in / fp32 out.
//
// R8 post-mortem: g pinned at ~31us = ~290 cyc/point = one serialized L2 gather
// per point; float4 packing + VGPR headroom changed nothing. R9: one query per
// WAVE, lane = gib row, unified branchless kernel form -> all idx/point loads
// are wave-uniform (readfirstlane-forced) -> scalar s_load path, no VMEM
// latency in the hot loop, acc = 1 VGPR/lane. In-kernel x2 repeat (anti-CSE
// via runtime z=0) so if the kernel is still ~31us it SURFACES in rocprof
// top-5 (2x31 > 41us fills) with counters; if fixed, dur_us drops to ~70s.

#define EPSF 1e-8f
#define LOG2E 1.4426950408889634f

constexpr int LAMT_STRIDE = 68;  // 64 + 4 pad floats; o-stride 4 banks -> 2-way max
constexpr int AS_STRIDE   = 68;
constexpr int NPTS        = 2 * 65536;
constexpr int REPS        = 2;   // measurement reps; endgame = 1

__global__ __launch_bounds__(256) void pack_points(
    const float* __restrict__ pts, float4* __restrict__ dst)
{
    int i = blockIdx.x * 256 + threadIdx.x;   // [0, NPTS)
    const float* p = pts + (size_t)i * 3;
    dst[i] = make_float4(p[0], p[1], p[2], 0.f);
}

__global__ __launch_bounds__(256, 4) void gib_kernel(
    const float4* __restrict__ pts4,    // (B*65536) packed x,y,z,_
    const float*  __restrict__ qc,      // (B, 8192, 3)
    const int*    __restrict__ sidx,    // (B, 8192, 32)
    const float*  __restrict__ cyp,     // (16,2)
    const float*  __restrict__ conep,   // (16,2)
    const float*  __restrict__ diskp,   // (16,2)
    const float*  __restrict__ ellp,    // (16,3)
    const float*  __restrict__ lam,     // (64,16)
    float*        __restrict__ out,     // (B, 8192, 16)
    int z)                              // 0 at runtime (anti-CSE for reps)
{
    __shared__ float lamT[16 * LAMT_STRIDE];  // lambda^T / 32   (4.4 KB)
    __shared__ float aS[4 * AS_STRIDE];       // per-wave gib sums (1.1 KB)

    const int tid = threadIdx.x;

    // ---- stage lambda^T: lamT[o][g] = lam[g][o] / 32 ----
    {
        int g = tid & 63, ob = tid >> 6;
#pragma unroll
        for (int it = 0; it < 4; it++) {
            int o = ob + it * 4;
            lamT[o * LAMT_STRIDE + g] = lam[g * 16 + o] * (1.0f / 32.0f);
        }
    }
    __syncthreads();

    const int l = tid & 63;                                  // lane = gib row
    const int w = __builtin_amdgcn_readfirstlane(tid >> 6);  // wave-in-block
    const int q = blockIdx.x * 4 + w;                        // query, uniform
    const int b = q >> 13;

    // ---- per-lane coefficients: arg = t*tm*nb, t = ax*rx2+ay*ry2+az*rz2+as*s+arz*rz+ac
    float ax, ay, az, as_, arz, ac, nb;
    const bool dosq = (l < 32);   // cy/cone square t; disk/ellip use t directly
    if (l < 16) {
        float c0 = cyp[2 * l], c1 = cyp[2 * l + 1];
        ax = 1.f; ay = 1.f; az = 0.f; as_ = 0.f; arz = 0.f; ac = -c0 * c0;
        nb = -LOG2E / (2.f * c1 * c1 + EPSF);
    } else if (l < 32) {
        int cc = l - 16;
        float k0 = conep[2 * cc], k1 = conep[2 * cc + 1];
        ax = 0.f; ay = 0.f; az = 0.f; as_ = 1.f; arz = -k0; ac = 0.f;
        nb = -LOG2E / (2.f * k1 * k1 + EPSF);
    } else if (l < 48) {
        int cc = l - 32;
        float d0 = diskp[2 * cc], d1 = diskp[2 * cc + 1];
        float A = -LOG2E / (d0 * d0 + EPSF);
        ax = A; ay = A; az = -LOG2E / (d1 * d1 + EPSF);
        as_ = 0.f; arz = 0.f; ac = 0.f; nb = 1.f;
    } else {
        int cc = l - 48;
        float e0 = ellp[3 * cc], e1 = ellp[3 * cc + 1], e2 = ellp[3 * cc + 2];
        ax = -LOG2E / (e0 * e0 + EPSF);
        ay = -LOG2E / (e1 * e1 + EPSF);
        az = -LOG2E / (e2 * e2 + EPSF);
        as_ = 0.f; arz = 0.f; ac = 0.f; nb = 1.f;
    }

    const float* qq = qc + q * 3;          // uniform -> scalar loads
    const float qx = qq[0], qy = qq[1], qz = qq[2];

    for (int rep = 0; rep < REPS; rep++) {
        const float4* pbz = pts4 + (b << 16) + z * rep;         // z=0: same base,
        const int4*   ip4 = (const int4*)(sidx + q * 32 + z * rep); // CSE-proof

        int idxs[32];
#pragma unroll
        for (int jc = 0; jc < 8; jc++) {
            int4 v = ip4[jc];              // uniform -> s_load_dwordx4
            idxs[4 * jc]     = __builtin_amdgcn_readfirstlane(v.x);
            idxs[4 * jc + 1] = __builtin_amdgcn_readfirstlane(v.y);
            idxs[4 * jc + 2] = __builtin_amdgcn_readfirstlane(v.z);
            idxs[4 * jc + 3] = __builtin_amdgcn_readfirstlane(v.w);
        }

        float acc = 0.f;
#pragma unroll 8
        for (int k = 0; k < 32; k++) {
            float4 p4 = pbz[idxs[k]];      // uniform addr -> s_load_dwordx4
            float rx = p4.x - qx;
            float ry = p4.y - qy;
            float rz = p4.z - qz;
            float rx2 = rx * rx, ry2 = ry * ry, rz2 = rz * rz;
            float s = __builtin_amdgcn_sqrtf(rx2 + ry2 + EPSF);
            float t = fmaf(ax, rx2, ac);
            t = fmaf(ay, ry2, t);
            t = fmaf(az, rz2, t);
            t = fmaf(as_, s, t);
            t = fmaf(arz, rz, t);
            float tm = dosq ? t : 1.0f;
            acc += __builtin_amdgcn_exp2f(t * tm * nb);
        }

        // ---- epilogue: wave-private LDS matvec ----
        aS[w * AS_STRIDE + l] = acc;       // gib row l of this query
        const int o = l & 15, p = l >> 4;  // observer, quarter
        const float* ap = &aS[w * AS_STRIDE + p * 16];
        const float* lp = &lamT[o * LAMT_STRIDE + p * 16];
        float part = 0.f;
#pragma unroll
        for (int j = 0; j < 4; j++) {
            float4 av = *(const float4*)(ap + 4 * j);  // broadcast per p-group
            float4 lv = *(const float4*)(lp + 4 * j);  // <=2-way conflict
            part = fmaf(av.x, lv.x, part);
            part = fmaf(av.y, lv.y, part);
            part = fmaf(av.z, lv.z, part);
            part = fmaf(av.w, lv.w, part);
        }
        part += __shfl_xor(part, 16, 64);  // merge the 4 quarters
        part += __shfl_xor(part, 32, 64);
        if (l < 16)
            out[q * 16 + l] = part;
    }
}

extern "C" void kernel_launch(void* const* d_in, const int* in_sizes, int n_in,
                              void* d_out, int out_size, void* d_ws, size_t ws_size,
                              hipStream_t stream) {
    const float* points = (const float*)d_in[0];
    const float* qc     = (const float*)d_in[1];
    const int*   sidx   = (const int*)d_in[2];
    // d_in[3] = mc_points: unused by the reference
    const float* cyp    = (const float*)d_in[4];
    const float* conep  = (const float*)d_in[5];
    const float* diskp  = (const float*)d_in[6];
    const float* ellp   = (const float*)d_in[7];
    const float* lam    = (const float*)d_in[8];
    float*       out    = (float*)d_out;
    float4*      pts4   = (float4*)d_ws;    // 2 MB of the 268 MB workspace

    hipLaunchKernelGGL(pack_points, dim3(NPTS / 256), dim3(256), 0, stream,
                       points, pts4);

    const int totalQ = 2 * 8192;            // 16384 queries, 1 per wave
    dim3 grid(totalQ / 4), block(256);      // 4096 blocks x 4 waves
    hipLaunchKernelGGL(gib_kernel, grid, block, 0, stream,
                       pts4, qc, sidx, cyp, conep, diskp, ellp, lam, out, 0);
}

// Round 10
// 105.148 us; speedup vs baseline: 1.2734x; 1.2734x over previous
//
#include <hip/hip_runtime.h>

// GIB layer: B=2, N=65536, M=8192, K=32; 16 each of cy/cone/disk/ellip gibs;
// out = mean_k(gib_vals) @ lambdas -> (B, M, 16). fp32 in / fp32 out.
//
// R9 post-mortem: wave-uniform scalar gathers fixed latency (VALUBusy 22->73%,
// g~33us); now issue-bound, model closes (~50cyc/point = 17 VALU x2 + 2 trans
// x8). R10: linearize ALL gib types onto basis (r4, r2, ry2, rz2, h=rz*s, 1):
//   cy  : nb(r2-c0^2)^2        = nb*r4 - 2c0^2 nb*r2 + nb*c0^4      (via r4)
//   cone: nb(s-k0 rz)^2        = nb*r2 - 2k0 nb*h + k0^2 nb*rz2 + nb*eps
//   disk/ellip: already linear (ellip via r2 and (ay-ax)*ry2)
// -> arg = single 5-fma chain + v_exp_f32; no cndmask/tm/nb muls (-3 VALU/pt).
// REPS=1 (diagnostics done; dur_us is the score).

#define EPSF 1e-8f
#define LOG2E 1.4426950408889634f

constexpr int LAMT_STRIDE = 68;  // 64 + 4 pad floats; o vs o+8 2-way max (free)
constexpr int AS_STRIDE   = 68;
constexpr int NPTS        = 2 * 65536;

__global__ __launch_bounds__(256) void pack_points(
    const float* __restrict__ pts, float4* __restrict__ dst)
{
    int i = blockIdx.x * 256 + threadIdx.x;   // [0, NPTS)
    const float* p = pts + (size_t)i * 3;
    dst[i] = make_float4(p[0], p[1], p[2], 0.f);
}

__global__ __launch_bounds__(256) void gib_kernel(
    const float4* __restrict__ pts4,    // (B*65536) packed x,y,z,_
    const float*  __restrict__ qc,      // (B, 8192, 3)
    const int*    __restrict__ sidx,    // (B, 8192, 32)
    const float*  __restrict__ cyp,     // (16,2)
    const float*  __restrict__ conep,   // (16,2)
    const float*  __restrict__ diskp,   // (16,2)
    const float*  __restrict__ ellp,    // (16,3)
    const float*  __restrict__ lam,     // (64,16)
    float*        __restrict__ out)     // (B, 8192, 16)
{
    __shared__ float lamT[16 * LAMT_STRIDE];  // lambda^T / 32     (4.4 KB)
    __shared__ float aS[4 * AS_STRIDE];       // per-wave gib sums (1.1 KB)

    const int tid = threadIdx.x;

    // ---- stage lambda^T: lamT[o][g] = lam[g][o] / 32 ----
    {
        int g = tid & 63, ob = tid >> 6;
#pragma unroll
        for (int it = 0; it < 4; it++) {
            int o = ob + it * 4;
            lamT[o * LAMT_STRIDE + g] = lam[g * 16 + o] * (1.0f / 32.0f);
        }
    }
    __syncthreads();

    const int l = tid & 63;                                  // lane = gib row
    const int w = __builtin_amdgcn_readfirstlane(tid >> 6);  // wave-in-block
    const int q = blockIdx.x * 4 + w;                        // query, uniform
    const int b = q >> 13;

    // ---- per-lane coefficients over basis (r4, r2, ry2, rz2, h, 1) ----
    // arg = c5*r4 + c4*r2 + c3*ry2 + c2*rz2 + c1*h + c0c ; contrib = exp2(arg)
    float c5, c4, c3, c2, c1, c0c;
    if (l < 16) {                       // cylinder
        float p0 = cyp[2 * l], p1 = cyp[2 * l + 1];
        float nb = -LOG2E / (2.f * p1 * p1 + EPSF);
        float c0sq = p0 * p0;
        c5 = nb; c4 = -2.f * c0sq * nb; c3 = 0.f; c2 = 0.f; c1 = 0.f;
        c0c = c0sq * c0sq * nb;
    } else if (l < 32) {                // cone
        int cc = l - 16;
        float k0 = conep[2 * cc], k1 = conep[2 * cc + 1];
        float nb = -LOG2E / (2.f * k1 * k1 + EPSF);
        c5 = 0.f; c4 = nb; c3 = 0.f; c2 = k0 * k0 * nb; c1 = -2.f * k0 * nb;
        c0c = nb * EPSF;
    } else if (l < 48) {                // disk
        int cc = l - 32;
        float d0 = diskp[2 * cc], d1 = diskp[2 * cc + 1];
        c5 = 0.f; c4 = -LOG2E / (d0 * d0 + EPSF); c3 = 0.f;
        c2 = -LOG2E / (d1 * d1 + EPSF); c1 = 0.f; c0c = 0.f;
    } else {                            // ellipsoid
        int cc = l - 48;
        float e0 = ellp[3 * cc], e1 = ellp[3 * cc + 1], e2 = ellp[3 * cc + 2];
        float ax = -LOG2E / (e0 * e0 + EPSF);
        float ay = -LOG2E / (e1 * e1 + EPSF);
        c5 = 0.f; c4 = ax; c3 = ay - ax; c2 = -LOG2E / (e2 * e2 + EPSF);
        c1 = 0.f; c0c = 0.f;
    }

    const float* qq = qc + q * 3;       // uniform -> scalar loads
    const float qx = qq[0], qy = qq[1], qz = qq[2];

    const float4* pb  = pts4 + (b << 16);
    const int4*   ip4 = (const int4*)(sidx + q * 32);

    int idxs[32];
#pragma unroll
    for (int jc = 0; jc < 8; jc++) {
        int4 v = ip4[jc];               // uniform -> s_load_dwordx4
        idxs[4 * jc]     = __builtin_amdgcn_readfirstlane(v.x);
        idxs[4 * jc + 1] = __builtin_amdgcn_readfirstlane(v.y);
        idxs[4 * jc + 2] = __builtin_amdgcn_readfirstlane(v.z);
        idxs[4 * jc + 3] = __builtin_amdgcn_readfirstlane(v.w);
    }

    float acc = 0.f;
#pragma unroll 8
    for (int k = 0; k < 32; k++) {
        float4 p4 = pb[idxs[k]];        // uniform addr -> scalar path
        float rx = p4.x - qx;
        float ry = p4.y - qy;
        float rz = p4.z - qz;
        float rx2 = rx * rx;
        float r2  = fmaf(ry, ry, rx2);
        float ry2 = ry * ry;
        float rz2 = rz * rz;
        float s   = __builtin_amdgcn_sqrtf(r2 + EPSF);
        float h   = rz * s;
        float r4  = r2 * r2;
        float arg = fmaf(c5, r4,
                    fmaf(c1, h,
                    fmaf(c4, r2,
                    fmaf(c3, ry2,
                    fmaf(c2, rz2, c0c)))));
        acc += __builtin_amdgcn_exp2f(arg);
    }

    // ---- epilogue: wave-private LDS matvec ----
    aS[w * AS_STRIDE + l] = acc;        // gib row l of this query
    const int o = l & 15, p = l >> 4;   // observer, quarter
    const float* ap = &aS[w * AS_STRIDE + p * 16];
    const float* lp = &lamT[o * LAMT_STRIDE + p * 16];
    float part = 0.f;
#pragma unroll
    for (int j = 0; j < 4; j++) {
        float4 av = *(const float4*)(ap + 4 * j);  // broadcast per p-group
        float4 lv = *(const float4*)(lp + 4 * j);  // <=2-way conflict (free)
        part = fmaf(av.x, lv.x, part);
        part = fmaf(av.y, lv.y, part);
        part = fmaf(av.z, lv.z, part);
        part = fmaf(av.w, lv.w, part);
    }
    part += __shfl_xor(part, 16, 64);   // merge the 4 quarters
    part += __shfl_xor(part, 32, 64);
    if (l < 16)
        out[q * 16 + l] = part;
}

extern "C" void kernel_launch(void* const* d_in, const int* in_sizes, int n_in,
                              void* d_out, int out_size, void* d_ws, size_t ws_size,
                              hipStream_t stream) {
    const float* points = (const float*)d_in[0];
    const float* qc     = (const float*)d_in[1];
    const int*   sidx   = (const int*)d_in[2];
    // d_in[3] = mc_points: unused by the reference
    const float* cyp    = (const float*)d_in[4];
    const float* conep  = (const float*)d_in[5];
    const float* diskp  = (const float*)d_in[6];
    const float* ellp   = (const float*)d_in[7];
    const float* lam    = (const float*)d_in[8];
    float*       out    = (float*)d_out;
    float4*      pts4   = (float4*)d_ws;    // 2 MB of the 268 MB workspace

    hipLaunchKernelGGL(pack_points, dim3(NPTS / 256), dim3(256), 0, stream,
                       points, pts4);

    const int totalQ = 2 * 8192;            // 16384 queries, 1 per wave
    dim3 grid(totalQ / 4), block(256);      // 4096 blocks x 4 waves
    hipLaunchKernelGGL(gib_kernel, grid, block, 0, stream,
                       pts4, qc, sidx, cyp, conep, diskp, ellp, lam, out);
}

// Round 11
// 88.867 us; speedup vs baseline: 1.5067x; 1.1832x over previous
//
#include <hip/hip_runtime.h>

// GIB layer: B=2, N=65536, M=8192, K=32; 16 each of cy/cone/disk/ellip gibs;
// out = mean_k(gib_vals) @ lambdas -> (B, M, 16). fp32 in / fp32 out.
//
// R10 post-mortem: harness charges ~20us per EXTRA kernel launch / d_ws use
// (R6 one-launch=84.2 vs R7 two=105.7, R10 pack+one=105.1). Winning shape =
// ONE kernel, no workspace. Device side: R7/R8 gather loop was ~290cyc/pt
// (unpipelined VMEM); R9 showed the VALU-bound regime works; R10's linearized
// coefficient math is verified. R11 = R6/R7 single-launch map + linearized
// 4/3-fma args + R7's verified LDS epilogue + explicit 1-ahead software
// pipeline on point loads with 128-VGPR headroom (launch_bounds(256,4)).

#define EPSF 1e-8f
#define LOG2E 1.4426950408889634f

constexpr int LAMT_STRIDE = 68;  // 64 + 4 pad floats (2-way max conflict, free)
constexpr int AS_STRIDE   = 72;  // 64 + 8 pad floats; rows 16B-aligned

__global__ __launch_bounds__(256, 4) void gib_kernel(
    const float* __restrict__ points,   // (B, 65536, 3)
    const float* __restrict__ qc,       // (B, 8192, 3)
    const int*   __restrict__ sidx,     // (B, 8192, 32)
    const float* __restrict__ cyp,      // (16,2)
    const float* __restrict__ conep,    // (16,2)
    const float* __restrict__ diskp,    // (16,2)
    const float* __restrict__ ellp,     // (16,3)
    const float* __restrict__ lam,      // (64,16)
    float*       __restrict__ out)      // (B, 8192, 16)
{
    __shared__ float lamT[16 * LAMT_STRIDE];  // lambda^T / 32   (4.4 KB)
    __shared__ float aS[8 * AS_STRIDE];       // per-query gib sums (2.3 KB)

    const int tid = threadIdx.x;

    // ---- stage lambda^T: lamT[o][g] = lam[g][o] / 32 ----
    {
        int g = tid & 63, ob = tid >> 6;
#pragma unroll
        for (int it = 0; it < 4; it++) {
            int o = ob + it * 4;
            lamT[o * LAMT_STRIDE + g] = lam[g * 16 + o] * (1.0f / 32.0f);
        }
    }
    __syncthreads();

    const int l  = tid & 63;
    const int c  = l & 31;               // gib pair: rows c and 32+c
    const int qh = l >> 5;               // query half of wave
    const int qb = (tid >> 6) * 2 + qh;  // query-in-block [0,8)
    const int q  = blockIdx.x * 8 + qb;  // global query
    const int b  = q >> 13;

    // ---- linearized per-lane coefficients (verified in R10) ----
    // argA = cA5*r4 + cA4*r2 + cA2*rz2 + cA1*h + cA0   (rows 0..31: cy | cone)
    // argB = cB4*r2 + cB3*ry2 + cB2*rz2               (rows 32..63: disk | ellip)
    float cA5, cA4, cA2, cA1, cA0, cB4, cB3, cB2;
    if (c < 16) {
        float p0 = cyp[2 * c], p1 = cyp[2 * c + 1];
        float nb = -LOG2E / (2.f * p1 * p1 + EPSF);
        float c0sq = p0 * p0;
        cA5 = nb; cA4 = -2.f * c0sq * nb; cA2 = 0.f; cA1 = 0.f;
        cA0 = c0sq * c0sq * nb;
        float d0 = diskp[2 * c], d1 = diskp[2 * c + 1];
        cB4 = -LOG2E / (d0 * d0 + EPSF); cB3 = 0.f;
        cB2 = -LOG2E / (d1 * d1 + EPSF);
    } else {
        int cc = c - 16;
        float k0 = conep[2 * cc], k1 = conep[2 * cc + 1];
        float nb = -LOG2E / (2.f * k1 * k1 + EPSF);
        cA5 = 0.f; cA4 = nb; cA2 = k0 * k0 * nb; cA1 = -2.f * k0 * nb;
        cA0 = nb * EPSF;
        float e0 = ellp[3 * cc], e1 = ellp[3 * cc + 1], e2 = ellp[3 * cc + 2];
        float ax = -LOG2E / (e0 * e0 + EPSF);
        float ay = -LOG2E / (e1 * e1 + EPSF);
        cB4 = ax; cB3 = ay - ax; cB2 = -LOG2E / (e2 * e2 + EPSF);
    }

    const float* qq = qc + q * 3;
    const float qx = qq[0], qy = qq[1], qz = qq[2];
    const float* pb = points + (size_t)(b << 16) * 3;

    // ---- hoist the 32 indices into registers (8 coalesced-broadcast int4) ----
    const int4* ip4 = (const int4*)(sidx + q * 32);
    int idx[32];
#pragma unroll
    for (int jc = 0; jc < 8; jc++) {
        int4 v = ip4[jc];
        idx[4 * jc]     = v.x;
        idx[4 * jc + 1] = v.y;
        idx[4 * jc + 2] = v.z;
        idx[4 * jc + 3] = v.w;
    }

    // ---- hot loop: 1-ahead software pipeline on the point gather ----
    float a0 = 0.f, a1 = 0.f;
    const float* p0p = pb + idx[0] * 3;
    float px = p0p[0], py = p0p[1], pz = p0p[2];
#pragma unroll
    for (int k = 0; k < 32; k++) {
        float cx = px, cyv = py, cz = pz;
        if (k < 31) {
            const float* pn = pb + idx[k + 1] * 3;   // issue next gather now
            px = pn[0]; py = pn[1]; pz = pn[2];
        }
        float rx = cx - qx;
        float ry = cyv - qy;
        float rz = cz - qz;
        float rx2 = rx * rx, ry2 = ry * ry, rz2 = rz * rz;
        float r2  = fmaf(ry, ry, rx2);
        float s   = __builtin_amdgcn_sqrtf(r2 + EPSF);
        float h   = rz * s;
        float r4  = r2 * r2;
        float argA = fmaf(cA5, r4,
                     fmaf(cA1, h,
                     fmaf(cA4, r2,
                     fmaf(cA2, rz2, cA0))));
        a0 += __builtin_amdgcn_exp2f(argA);
        float argB = fmaf(cB4, r2, fmaf(cB3, ry2, cB2 * rz2));
        a1 += __builtin_amdgcn_exp2f(argB);
    }

    // ---- epilogue: wave-private LDS lambda-reduction (verified in R7) ----
    aS[qb * AS_STRIDE + c]      = a0;    // gib row c
    aS[qb * AS_STRIDE + 32 + c] = a1;    // gib row 32+c

    const int o = c & 15;                // observer this lane produces
    const int hh = c >> 4;               // which half of the 64 gibs to sum
    const float* ap = &aS[qb * AS_STRIDE + hh * 32];
    const float* lp = &lamT[o * LAMT_STRIDE + hh * 32];

    float part = 0.f;
#pragma unroll
    for (int j = 0; j < 8; j++) {
        float4 av = *(const float4*)(ap + j * 4);   // broadcast across o-lanes
        float4 lv = *(const float4*)(lp + j * 4);   // <=2-way conflict (free)
        part = fmaf(av.x, lv.x, part);
        part = fmaf(av.y, lv.y, part);
        part = fmaf(av.z, lv.z, part);
        part = fmaf(av.w, lv.w, part);
    }
    part += __shfl_xor(part, 16, 64);    // merge halves (same o, same query)

    if (hh == 0)
        out[q * 16 + o] = part;
}

extern "C" void kernel_launch(void* const* d_in, const int* in_sizes, int n_in,
                              void* d_out, int out_size, void* d_ws, size_t ws_size,
                              hipStream_t stream) {
    const float* points = (const float*)d_in[0];
    const float* qc     = (const float*)d_in[1];
    const int*   sidx   = (const int*)d_in[2];
    // d_in[3] = mc_points: unused by the reference
    const float* cyp    = (const float*)d_in[4];
    const float* conep  = (const float*)d_in[5];
    const float* diskp  = (const float*)d_in[6];
    const float* ellp   = (const float*)d_in[7];
    const float* lam    = (const float*)d_in[8];
    float*       out    = (float*)d_out;

    const int totalQ = 2 * 8192;            // B*M = 16384, 8 queries/block
    dim3 grid(totalQ / 8), block(256);      // 2048 blocks, ONE launch, no d_ws
    hipLaunchKernelGGL(gib_kernel, grid, block, 0, stream,
                       points, qc, sidx, cyp, conep, diskp, ellp, lam, out);
}